// Round 10
// baseline (127.133 us; speedup 1.0000x reference)
//
#include <hip/hip_runtime.h>

#define SMOOTH 1e-5f

typedef float floatx4 __attribute__((ext_vector_type(4)));

// ws[scale][img][5] = {C, S, inter, z_sum, p_sum}

__device__ __forceinline__ float wave_reduce(float v) {
#pragma unroll
    for (int off = 32; off; off >>= 1) v += __shfl_down(v, off, 64);
    return v;
}

__device__ __forceinline__ float sigmoidf(float x) {
    return 1.f / (1.f + __expf(-x));
}

__device__ __forceinline__ unsigned pack8(int4 a, int4 b) {
    return (unsigned)(a.x != 0)        | ((unsigned)(a.y != 0) << 1) |
           ((unsigned)(a.z != 0) << 2) | ((unsigned)(a.w != 0) << 3) |
           ((unsigned)(b.x != 0) << 4) | ((unsigned)(b.y != 0) << 5) |
           ((unsigned)(b.z != 0) << 6) | ((unsigned)(b.w != 0) << 7);
}
__device__ __forceinline__ unsigned pack4(int4 a, int4 b) {   // even elements
    return (unsigned)(a.x != 0)        | ((unsigned)(a.z != 0) << 1) |
           ((unsigned)(b.x != 0) << 2) | ((unsigned)(b.z != 0) << 3);
}
__device__ __forceinline__ unsigned pack2(int a, int b) {
    return (unsigned)(a != 0) | ((unsigned)(b != 0) << 1);
}

// boundary pixels in row c given rows u (above), d (below); W px/lane packed
template<int W>
__device__ __forceinline__ int stencil_cnt(unsigned u, unsigned c, unsigned d, int lane)
{
    unsigned pv = __shfl_up(c, 1);
    unsigned nx = __shfl_down(c, 1);
    if (lane == 0)  pv = 0;
    if (lane == 63) nx = 0;
    const unsigned M = (1u << W) - 1u;
    unsigned lv = ((c << 1) | ((pv >> (W - 1)) & 1u)) & M;
    unsigned rv = ((c >> 1) | ((nx & 1u) << (W - 1))) & M;
    return __popc(c & ~(u & d & lv & rv));
}

// One dispatch, two block families (1792 blocks = 7/CU, all co-resident):
//  blk <1344: STREAMING (S,I,Z,P): flat linear float4+int4 loads, m13-shaped.
//    scale0: 1024 blocks (32/img), scale1: 256 (8/img), scale2: 64 (2/img);
//    every block = 2048 quads = 8 iters x 256 threads.
//  blk>=1344: BOUNDARY (C only, targets only, LLC-hot): 448 blocks, waves 0,1
//    each own a 32-row strip; sliding packed-bit stencil, 1 row load/step.
__global__ __launch_bounds__(256) void bdou_main(
    const float* __restrict__ l0, const float* __restrict__ l1,
    const float* __restrict__ l2, const int* __restrict__ tgt,
    float* __restrict__ ws)
{
    const int blk = blockIdx.x;
    const int tid = threadIdx.x;
    const int w = tid >> 6, lane = tid & 63;

    if (blk < 1344) {
        // ---------------- streaming: S, I, Z, P ----------------
        int scale, img, chunk;
        if (blk < 1024)      { scale = 0; img = blk >> 5; chunk = blk & 31; }
        else if (blk < 1280) { int b = blk - 1024; scale = 1; img = b >> 3; chunk = b & 7; }
        else                 { int b = blk - 1280; scale = 2; img = b >> 1; chunk = b & 1; }
        const int* __restrict__ T = tgt + (size_t)img * 262144;
        int cS = 0; float aI = 0.f, aZ = 0.f, aP = 0.f;
        const int qbase = chunk * 2048 + tid;

        if (scale == 0) {
            const float* __restrict__ L = l0 + (size_t)img * 262144;
#pragma unroll
            for (int it = 0; it < 8; ++it) {
                int p = (qbase + it * 256) * 4;
                floatx4 lg = *(const floatx4*)(L + p);
                int4    tv = *(const int4*)(T + p);
                float pr[4] = {sigmoidf(lg.x), sigmoidf(lg.y), sigmoidf(lg.z), sigmoidf(lg.w)};
                int   tb[4] = {tv.x != 0, tv.y != 0, tv.z != 0, tv.w != 0};
#pragma unroll
                for (int j = 0; j < 4; ++j) {
                    cS += tb[j];
                    aI += pr[j] * (float)tb[j];
                    aZ += pr[j] * pr[j];
                    aP += pr[j];
                }
            }
        } else if (scale == 1) {
            const float* __restrict__ L = l1 + (size_t)img * 65536;
#pragma unroll
            for (int it = 0; it < 8; ++it) {
                int p = (qbase + it * 256) * 4;          // ds pixel
                int y = p >> 8, x = p & 255;
                floatx4 lg = *(const floatx4*)(L + (size_t)y * 256 + x);
                const int* r = T + (size_t)(2 * y) * 512 + 2 * x;
                int4 a = *(const int4*)(r);
                int4 b = *(const int4*)(r + 4);
                float pr[4] = {sigmoidf(lg.x), sigmoidf(lg.y), sigmoidf(lg.z), sigmoidf(lg.w)};
                int   tb[4] = {a.x != 0, a.z != 0, b.x != 0, b.z != 0};
#pragma unroll
                for (int j = 0; j < 4; ++j) {
                    cS += tb[j];
                    aI += pr[j] * (float)tb[j];
                    aZ += pr[j] * pr[j];
                    aP += pr[j];
                }
            }
        } else {
            const float* __restrict__ L = l2 + (size_t)img * 16384;
#pragma unroll
            for (int it = 0; it < 8; ++it) {
                int p = (qbase + it * 256) * 4;          // ds pixel
                int y = p >> 7, x = p & 127;
                floatx4 lg = *(const floatx4*)(L + (size_t)y * 128 + x);
                const int* r = T + (size_t)(4 * y) * 512 + 4 * x;
                int t0 = r[0], t1 = r[4], t2 = r[8], t3 = r[12];
                float pr[4] = {sigmoidf(lg.x), sigmoidf(lg.y), sigmoidf(lg.z), sigmoidf(lg.w)};
                int   tb[4] = {t0 != 0, t1 != 0, t2 != 0, t3 != 0};
#pragma unroll
                for (int j = 0; j < 4; ++j) {
                    cS += tb[j];
                    aI += pr[j] * (float)tb[j];
                    aZ += pr[j] * pr[j];
                    aP += pr[j];
                }
            }
        }

        __shared__ float red[4][4];
        float vals[4] = {(float)cS, aI, aZ, aP};
#pragma unroll
        for (int k = 0; k < 4; ++k) vals[k] = wave_reduce(vals[k]);
        if (lane == 0) {
#pragma unroll
            for (int k = 0; k < 4; ++k) red[w][k] = vals[k];
        }
        __syncthreads();
        if (tid < 4) {
            float s = red[0][tid] + red[1][tid] + red[2][tid] + red[3][tid];
            atomicAdd(&ws[(scale * 32 + img) * 5 + 1 + tid], s);
        }
    } else {
        // ---------------- boundary: C only ----------------
        if (w >= 2) return;                       // waves 2,3 idle
        const int task = (blk - 1344) * 2 + w;    // [0,896)
        int scale, img, strip;
        if (task < 512)      { scale = 0; img = task >> 4; strip = task & 15; }
        else if (task < 768) { int b = task - 512; scale = 1; img = b >> 3; strip = b & 7; }
        else                 { int b = task - 768; scale = 2; img = b >> 2; strip = b & 3; }
        const int* __restrict__ T = tgt + (size_t)img * 262144 + lane * 8;
        const int y0 = strip * 32;
        int cC = 0;

        if (scale == 0) {
            unsigned rp = 0, rc;
            if (y0 > 0) {
                int4 a = *(const int4*)(T + (size_t)(y0 - 1) * 512);
                int4 b = *(const int4*)(T + (size_t)(y0 - 1) * 512 + 4);
                rp = pack8(a, b);
            }
            {
                int4 a = *(const int4*)(T + (size_t)y0 * 512);
                int4 b = *(const int4*)(T + (size_t)y0 * 512 + 4);
                rc = pack8(a, b);
            }
            int4 f0 = *(const int4*)(T + (size_t)(y0 + 1) * 512);
            int4 f1 = *(const int4*)(T + (size_t)(y0 + 1) * 512 + 4);
            for (int i = 0; i < 32; ++i) {
                int y = y0 + i;
                unsigned rn = (y < 511) ? pack8(f0, f1) : 0u;
                int yn = (y + 2 <= 511) ? y + 2 : 511;
                f0 = *(const int4*)(T + (size_t)yn * 512);
                f1 = *(const int4*)(T + (size_t)yn * 512 + 4);
                cC += stencil_cnt<8>(rp, rc, rn, lane);
                rp = rc; rc = rn;
            }
        } else if (scale == 1) {
            unsigned rp = 0, rc;
            if (y0 > 0) {
                int4 a = *(const int4*)(T + (size_t)(2 * (y0 - 1)) * 512);
                int4 b = *(const int4*)(T + (size_t)(2 * (y0 - 1)) * 512 + 4);
                rp = pack4(a, b);
            }
            {
                int4 a = *(const int4*)(T + (size_t)(2 * y0) * 512);
                int4 b = *(const int4*)(T + (size_t)(2 * y0) * 512 + 4);
                rc = pack4(a, b);
            }
            int4 f0 = *(const int4*)(T + (size_t)(2 * (y0 + 1)) * 512);
            int4 f1 = *(const int4*)(T + (size_t)(2 * (y0 + 1)) * 512 + 4);
            for (int i = 0; i < 32; ++i) {
                int y = y0 + i;
                unsigned rn = (y < 255) ? pack4(f0, f1) : 0u;
                int yn = (y + 2 <= 255) ? y + 2 : 255;
                f0 = *(const int4*)(T + (size_t)(2 * yn) * 512);
                f1 = *(const int4*)(T + (size_t)(2 * yn) * 512 + 4);
                cC += stencil_cnt<4>(rp, rc, rn, lane);
                rp = rc; rc = rn;
            }
        } else {
            unsigned rp = 0, rc;
            if (y0 > 0) rp = pack2(T[(size_t)(4 * (y0 - 1)) * 512], T[(size_t)(4 * (y0 - 1)) * 512 + 4]);
            rc = pack2(T[(size_t)(4 * y0) * 512], T[(size_t)(4 * y0) * 512 + 4]);
            int f0 = T[(size_t)(4 * (y0 + 1)) * 512];
            int f1 = T[(size_t)(4 * (y0 + 1)) * 512 + 4];
            for (int i = 0; i < 32; ++i) {
                int y = y0 + i;
                unsigned rn = (y < 127) ? pack2(f0, f1) : 0u;
                int yn = (y + 2 <= 127) ? y + 2 : 127;
                f0 = T[(size_t)(4 * yn) * 512];
                f1 = T[(size_t)(4 * yn) * 512 + 4];
                cC += stencil_cnt<2>(rp, rc, rn, lane);
                rp = rc; rc = rn;
            }
        }

        float c = wave_reduce((float)cC);
        if (lane == 0) atomicAdd(&ws[(scale * 32 + img) * 5 + 0], c);
    }
}

// 128 threads: tid<96 -> one (scale,img) pair each; wave+LDS reduce.
__global__ void bdou_final(const float* __restrict__ ws,
                           const float* __restrict__ valid_mask,
                           float* __restrict__ out)
{
    int tid = threadIdx.x;
    float contrib = 0.f, cpart = 0.f;
    if (tid < 96) {
        int s = tid >> 5, i = tid & 31;
        const float* w = ws + tid * 5;
        float C = w[0], S = w[1], I = w[2], Z = w[3], P = w[4];
        float valid = (valid_mask[i] >= 0.5f) ? 1.f : 0.f;
        float alpha = fminf(2.f * (1.f - (C + SMOOTH) / (S + SMOOTH)) - 1.f, 0.8f);
        float dou = (Z + S - 2.f * I + SMOOTH) /
                    (Z + S - (1.f + alpha) * I + SMOOTH);
        const float wts[3]  = {4.f / 7.f, 2.f / 7.f, 1.f / 7.f};
        const float pixc[3] = {262144.f, 65536.f, 16384.f};
        float per = (S > 0.f) ? dou : (P / pixc[s]);
        contrib = wts[s] * per * valid;
        if (tid < 32) cpart = valid;
    }
    contrib = wave_reduce(contrib);
    cpart   = wave_reduce(cpart);
    __shared__ float sm[2][2];
    int wv = tid >> 6, ln = tid & 63;
    if (ln == 0) { sm[wv][0] = contrib; sm[wv][1] = cpart; }
    __syncthreads();
    if (tid == 0) {
        float tot = sm[0][0] + sm[1][0];
        float cnt = sm[0][1] + sm[1][1];
        out[0] = (cnt > 0.f) ? tot / cnt : 0.f;
    }
}

extern "C" void kernel_launch(void* const* d_in, const int* in_sizes, int n_in,
                              void* d_out, int out_size, void* d_ws, size_t ws_size,
                              hipStream_t stream) {
    const float* l0 = (const float*)d_in[0];
    const float* l1 = (const float*)d_in[1];
    const float* l2 = (const float*)d_in[2];
    const int*   tg = (const int*)d_in[3];
    const float* vm = (const float*)d_in[4];
    float* ws = (float*)d_ws;

    (void)hipMemsetAsync(ws, 0, 3 * 32 * 5 * sizeof(float), stream);
    bdou_main<<<1792, 256, 0, stream>>>(l0, l1, l2, tg, ws);
    bdou_final<<<1, 128, 0, stream>>>(ws, vm, (float*)d_out);
}

// Round 11
// 111.662 us; speedup vs baseline: 1.1386x; 1.1386x over previous
//
#include <hip/hip_runtime.h>

#define SMOOTH 1e-5f

typedef float floatx4 __attribute__((ext_vector_type(4)));
typedef float floatx2 __attribute__((ext_vector_type(2)));

// ws[scale][img][5] = {C, S, inter, z_sum, p_sum}

__device__ __forceinline__ float wave_reduce(float v) {
#pragma unroll
    for (int off = 32; off; off >>= 1) v += __shfl_down(v, off, 64);
    return v;
}

__device__ __forceinline__ float sigmoidf(float x) {
    return 1.f / (1.f + __expf(-x));
}

__device__ __forceinline__ unsigned pack8(int4 a, int4 b) {
    return (unsigned)(a.x != 0)        | ((unsigned)(a.y != 0) << 1) |
           ((unsigned)(a.z != 0) << 2) | ((unsigned)(a.w != 0) << 3) |
           ((unsigned)(b.x != 0) << 4) | ((unsigned)(b.y != 0) << 5) |
           ((unsigned)(b.z != 0) << 6) | ((unsigned)(b.w != 0) << 7);
}
// ds1 bits (even cols): byte bits {0,2,4,6} -> {0,1,2,3}
__device__ __forceinline__ unsigned even4(unsigned b) {
    return (b & 1u) | ((b >> 1) & 2u) | ((b >> 2) & 4u) | ((b >> 3) & 8u);
}
// ds2 bits (cols 0,4): byte bits {0,4} -> {0,1}
__device__ __forceinline__ unsigned ext2(unsigned b) {
    return (b & 1u) | ((b >> 3) & 2u);
}

// boundary count in row c (W px/lane packed) given up/down rows u,d
template<int W>
__device__ __forceinline__ int stencil_cnt(unsigned u, unsigned c, unsigned d, int lane)
{
    unsigned pv = __shfl_up(c, 1);
    unsigned nx = __shfl_down(c, 1);
    if (lane == 0)  pv = 0;
    if (lane == 63) nx = 0;
    const unsigned M = (1u << W) - 1u;
    unsigned lv = ((c << 1) | ((pv >> (W - 1)) & 1u)) & M;
    unsigned rv = ((c >> 1) | ((nx & 1u) << (W - 1))) & M;
    return __popc(c & ~(u & d & lv & rv));
}

__device__ __forceinline__ void acc_row8(floatx4 a, floatx4 b, unsigned bits,
                                         float& I, float& Z, float& P) {
    float pr[8] = {sigmoidf(a.x), sigmoidf(a.y), sigmoidf(a.z), sigmoidf(a.w),
                   sigmoidf(b.x), sigmoidf(b.y), sigmoidf(b.z), sigmoidf(b.w)};
#pragma unroll
    for (int j = 0; j < 8; ++j) {
        I += ((bits >> j) & 1u) ? pr[j] : 0.f;
        Z += pr[j] * pr[j];
        P += pr[j];
    }
}
__device__ __forceinline__ void acc_row4(floatx4 a, unsigned bits,
                                         float& I, float& Z, float& P) {
    float pr[4] = {sigmoidf(a.x), sigmoidf(a.y), sigmoidf(a.z), sigmoidf(a.w)};
#pragma unroll
    for (int j = 0; j < 4; ++j) {
        I += ((bits >> j) & 1u) ? pr[j] : 0.f;
        Z += pr[j] * pr[j];
        P += pr[j];
    }
}
__device__ __forceinline__ void acc_row2(floatx2 a, unsigned bits,
                                         float& I, float& Z, float& P) {
    float pr[2] = {sigmoidf(a.x), sigmoidf(a.y)};
#pragma unroll
    for (int j = 0; j < 2; ++j) {
        I += ((bits >> j) & 1u) ? pr[j] : 0.f;
        Z += pr[j] * pr[j];
        P += pr[j];
    }
}

// UNIFIED single pass. 1024 blocks x 256 thr (16 waves/CU). Wave = full row
// width (64 lanes x 8 px); each wave owns a 4-row full-res strip and computes
// ALL 15 partials from it: ds grids nest in-lane (ds1 = even bits, ds2 = bits
// 0/4), so one linear row stream serves every scale's stencil + sums.
// Per wave: 8 tgt rows + 4 l0 rows + 2 l1 rows + 1 l2 row, all coalesced,
// each global byte read exactly once per consumer. y0 = multiple of 4.
__global__ __launch_bounds__(256) void bdou_unified(
    const float* __restrict__ l0, const float* __restrict__ l1,
    const float* __restrict__ l2, const int* __restrict__ tgt,
    float* __restrict__ ws)
{
    const int blk  = blockIdx.x;
    const int tid  = threadIdx.x;
    const int w    = tid >> 6, lane = tid & 63;
    const int img  = blk >> 5;
    const int y0   = (blk & 31) * 16 + w * 4;          // 0..508, mult of 4

    const int*   T  = tgt + (size_t)img * 262144 + lane * 8;
    const float* L0 = l0  + (size_t)img * 262144 + lane * 8;
    const float* L1 = l1  + (size_t)img * 65536  + lane * 4;
    const float* L2 = l2  + (size_t)img * 16384  + lane * 2;

    const int ym4 = (y0 >= 4) ? y0 - 4 : 0;            // clamped halo rows
    const int ym2 = (y0 >= 2) ? y0 - 2 : 0;
    const int ym1 = (y0 >= 1) ? y0 - 1 : 0;
    const int yp4 = (y0 + 4 <= 511) ? y0 + 4 : 511;
    const unsigned mu = (y0 > 0)   ? 0xFFu : 0u;       // up-halo valid
    const unsigned md = (y0 < 508) ? 0xFFu : 0u;       // down-halo valid

    // ---- issue all 27 loads (independent addresses) ----
    int4 tA0 = *(const int4*)(T + (size_t)ym4 * 512), tA1 = *(const int4*)(T + (size_t)ym4 * 512 + 4);
    int4 tB0 = *(const int4*)(T + (size_t)ym2 * 512), tB1 = *(const int4*)(T + (size_t)ym2 * 512 + 4);
    int4 tC0 = *(const int4*)(T + (size_t)ym1 * 512), tC1 = *(const int4*)(T + (size_t)ym1 * 512 + 4);
    int4 t00 = *(const int4*)(T + (size_t)(y0    ) * 512), t01 = *(const int4*)(T + (size_t)(y0    ) * 512 + 4);
    int4 t10 = *(const int4*)(T + (size_t)(y0 + 1) * 512), t11 = *(const int4*)(T + (size_t)(y0 + 1) * 512 + 4);
    int4 t20 = *(const int4*)(T + (size_t)(y0 + 2) * 512), t21 = *(const int4*)(T + (size_t)(y0 + 2) * 512 + 4);
    int4 t30 = *(const int4*)(T + (size_t)(y0 + 3) * 512), t31 = *(const int4*)(T + (size_t)(y0 + 3) * 512 + 4);
    int4 tD0 = *(const int4*)(T + (size_t)yp4 * 512), tD1 = *(const int4*)(T + (size_t)yp4 * 512 + 4);
    floatx4 g00 = *(const floatx4*)(L0 + (size_t)(y0    ) * 512), g01 = *(const floatx4*)(L0 + (size_t)(y0    ) * 512 + 4);
    floatx4 g10 = *(const floatx4*)(L0 + (size_t)(y0 + 1) * 512), g11 = *(const floatx4*)(L0 + (size_t)(y0 + 1) * 512 + 4);
    floatx4 g20 = *(const floatx4*)(L0 + (size_t)(y0 + 2) * 512), g21 = *(const floatx4*)(L0 + (size_t)(y0 + 2) * 512 + 4);
    floatx4 g30 = *(const floatx4*)(L0 + (size_t)(y0 + 3) * 512), g31 = *(const floatx4*)(L0 + (size_t)(y0 + 3) * 512 + 4);
    floatx4 h0  = *(const floatx4*)(L1 + (size_t)(y0 / 2    ) * 256);
    floatx4 h1  = *(const floatx4*)(L1 + (size_t)(y0 / 2 + 1) * 256);
    floatx2 q0  = *(const floatx2*)(L2 + (size_t)(y0 / 4) * 128);

    // ---- pack target bits ----
    unsigned bm4 = pack8(tA0, tA1) & mu;   // scale2 up (full row y0-4)
    unsigned bm2 = pack8(tB0, tB1) & mu;   // scale1 up (y0-2)
    unsigned bm1 = pack8(tC0, tC1) & mu;   // scale0 up (y0-1)
    unsigned b0  = pack8(t00, t01);
    unsigned b1  = pack8(t10, t11);
    unsigned b2  = pack8(t20, t21);
    unsigned b3  = pack8(t30, t31);
    unsigned bp4 = pack8(tD0, tD1) & md;   // shared down halo (y0+4)

    int cC0, cS0, cC1, cS1, cC2, cS2;
    float aI0 = 0.f, aZ0 = 0.f, aP0 = 0.f;
    float aI1 = 0.f, aZ1 = 0.f, aP1 = 0.f;
    float aI2 = 0.f, aZ2 = 0.f, aP2 = 0.f;

    // ---- scale 0 ----
    cS0 = __popc(b0) + __popc(b1) + __popc(b2) + __popc(b3);
    cC0 = stencil_cnt<8>(bm1, b0, b1, lane) + stencil_cnt<8>(b0, b1, b2, lane) +
          stencil_cnt<8>(b1, b2, b3, lane) + stencil_cnt<8>(b2, b3, bp4, lane);
    acc_row8(g00, g01, b0, aI0, aZ0, aP0);
    acc_row8(g10, g11, b1, aI0, aZ0, aP0);
    acc_row8(g20, g21, b2, aI0, aZ0, aP0);
    acc_row8(g30, g31, b3, aI0, aZ0, aP0);

    // ---- scale 1 (ds rows y0/2, y0/2+1 <- full rows y0, y0+2) ----
    {
        unsigned cu = even4(bm2), c0 = even4(b0), c1 = even4(b2), cd = even4(bp4);
        cS1 = __popc(c0) + __popc(c1);
        cC1 = stencil_cnt<4>(cu, c0, c1, lane) + stencil_cnt<4>(c0, c1, cd, lane);
        acc_row4(h0, c0, aI1, aZ1, aP1);
        acc_row4(h1, c1, aI1, aZ1, aP1);
    }

    // ---- scale 2 (ds row y0/4 <- full row y0) ----
    {
        unsigned zu = ext2(bm4), z = ext2(b0), zd = ext2(bp4);
        cS2 = __popc(z);
        cC2 = stencil_cnt<2>(zu, z, zd, lane);
        acc_row2(q0, z, aI2, aZ2, aP2);
    }

    // ---- block reduce 15 partials, atomic into ws ----
    float vals[15] = {(float)cC0, (float)cS0, aI0, aZ0, aP0,
                      (float)cC1, (float)cS1, aI1, aZ1, aP1,
                      (float)cC2, (float)cS2, aI2, aZ2, aP2};
    __shared__ float red[4][15];
#pragma unroll
    for (int k = 0; k < 15; ++k) vals[k] = wave_reduce(vals[k]);
    if (lane == 0) {
#pragma unroll
        for (int k = 0; k < 15; ++k) red[w][k] = vals[k];
    }
    __syncthreads();
    if (tid < 15) {
        float s = red[0][tid] + red[1][tid] + red[2][tid] + red[3][tid];
        int sc = tid / 5, k = tid - sc * 5;
        atomicAdd(&ws[(sc * 32 + img) * 5 + k], s);
    }
}

// 128 threads: tid<96 -> one (scale,img) pair each; wave+LDS reduce.
__global__ void bdou_final(const float* __restrict__ ws,
                           const float* __restrict__ valid_mask,
                           float* __restrict__ out)
{
    int tid = threadIdx.x;
    float contrib = 0.f, cpart = 0.f;
    if (tid < 96) {
        int s = tid >> 5, i = tid & 31;
        const float* w = ws + tid * 5;
        float C = w[0], S = w[1], I = w[2], Z = w[3], P = w[4];
        float valid = (valid_mask[i] >= 0.5f) ? 1.f : 0.f;
        float alpha = fminf(2.f * (1.f - (C + SMOOTH) / (S + SMOOTH)) - 1.f, 0.8f);
        float dou = (Z + S - 2.f * I + SMOOTH) /
                    (Z + S - (1.f + alpha) * I + SMOOTH);
        const float wts[3]  = {4.f / 7.f, 2.f / 7.f, 1.f / 7.f};
        const float pixc[3] = {262144.f, 65536.f, 16384.f};
        float per = (S > 0.f) ? dou : (P / pixc[s]);
        contrib = wts[s] * per * valid;
        if (tid < 32) cpart = valid;
    }
    contrib = wave_reduce(contrib);
    cpart   = wave_reduce(cpart);
    __shared__ float sm[2][2];
    int wv = tid >> 6, ln = tid & 63;
    if (ln == 0) { sm[wv][0] = contrib; sm[wv][1] = cpart; }
    __syncthreads();
    if (tid == 0) {
        float tot = sm[0][0] + sm[1][0];
        float cnt = sm[0][1] + sm[1][1];
        out[0] = (cnt > 0.f) ? tot / cnt : 0.f;
    }
}

extern "C" void kernel_launch(void* const* d_in, const int* in_sizes, int n_in,
                              void* d_out, int out_size, void* d_ws, size_t ws_size,
                              hipStream_t stream) {
    const float* l0 = (const float*)d_in[0];
    const float* l1 = (const float*)d_in[1];
    const float* l2 = (const float*)d_in[2];
    const int*   tg = (const int*)d_in[3];
    const float* vm = (const float*)d_in[4];
    float* ws = (float*)d_ws;

    (void)hipMemsetAsync(ws, 0, 3 * 32 * 5 * sizeof(float), stream);
    bdou_unified<<<1024, 256, 0, stream>>>(l0, l1, l2, tg, ws);
    bdou_final<<<1, 128, 0, stream>>>(ws, vm, (float*)d_out);
}